// Round 8
// baseline (275.749 us; speedup 1.0000x reference)
//
#include <hip/hip_runtime.h>
#include <hip/hip_bf16.h>
#include <stdint.h>

// StrideGraphSAGE on MI355X (gfx950).
// h_l = elu(agg @ Wl[l] + bl[l] + nodes @ Wr[l]); out = concat(h_0..h_3, x) along C.
// agg is nonzero only for rows < 1089 (un-offset edge_index bug in the reference);
// the edge set is the deterministic stride-2 grid pattern -> computed analytically.
//
// ROUND 8 = ROUND 4 EXACT + duplicated gemm launch (timing ablation: the 2nd
// gemm writes identical bytes; dur_us - 157 gives the warm GEMM cost directly).

#define C_DIM 256
#define GRID_G 33
#define N_NODES 1089
#define BATCH 64
#define TOTAL (BATCH * N_NODES)     // 69696
#define M_PAD 69760                 // 545 * 128
#define CN (C_DIM * N_NODES)        // 278784
#define OUT_STRIDE_B (5 * CN)       // 1393920
#define NCOLS 1024                  // 4 layers * 256
#define AGG_ROWS 1152               // 9*128, zero-padded past 1089

using bf16 = __hip_bfloat16;
typedef __attribute__((ext_vector_type(8))) short short8;
typedef __attribute__((ext_vector_type(4))) float f32x4;

// ---- workspace layout (bytes) ----
#define NODES_BYTES ((size_t)M_PAD * C_DIM * 2)      // 35,717,120
#define OFF_NODES   ((size_t)0)
#define OFF_AGGB    (NODES_BYTES)
#define AGGB_BYTES  ((size_t)AGG_ROWS * C_DIM * 2)   // 589,824
#define OFF_WLT     (OFF_AGGB + AGGB_BYTES)
#define WT_BYTES    ((size_t)NCOLS * C_DIM * 2)      // 524,288
#define OFF_WRT     (OFF_WLT + WT_BYTES)

__device__ __forceinline__ void gload16(void* lds, const void* g) {
    __builtin_amdgcn_global_load_lds(
        (const __attribute__((address_space(1))) uint32_t*)g,
        (__attribute__((address_space(3))) uint32_t*)lds,
        16, 0, 0);
}

// ---- fused prep: blocks 0..127 transpose W -> WT bf16; blocks 128..1279:
// x [B,C,N] f32 -> nodes [B*N, C] bf16, and copy x into out concat-block 4 ----
__global__ __launch_bounds__(256)
void prep_kernel(const float* __restrict__ x,
                 const float* __restrict__ Wl, const float* __restrict__ Wr,
                 bf16* __restrict__ nodes, bf16* __restrict__ WlT, bf16* __restrict__ WrT,
                 float* __restrict__ out)
{
    __shared__ char smem[33792];
    const int t = threadIdx.x;
    const int bid = blockIdx.x;
    if (bid < 128) {
        // ---- weight transpose: W[l][k][c] f32 -> WT[l*256+c][k] bf16 ----
        float (*tile)[65] = (float(*)[65])smem;
        const int sel = bid & 1;
        const int l = (bid >> 1) & 3;
        const int kt = ((bid >> 3) & 3) * 64;
        const int ct = ((bid >> 5) & 3) * 64;
        const float* W = sel ? Wr : Wl;
        bf16* WT = sel ? WrT : WlT;
        const int tc = t & 63;
        const int tk = t >> 6;
#pragma unroll
        for (int i = 0; i < 16; ++i) {
            int kl = i * 4 + tk;
            tile[kl][tc] = W[((size_t)(l * 256 + kt + kl)) * 256 + ct + tc];
        }
        __syncthreads();
#pragma unroll
        for (int i = 0; i < 16; ++i) {
            int cl = i * 4 + tk;
            WT[((size_t)(l * 256 + ct + cl)) * 256 + kt + tc] = __float2bfloat16(tile[tc][cl]);
        }
    } else {
        // ---- x transpose ----
        bf16 (*tile)[66] = (bf16(*)[66])smem;   // [c][n], row stride 132B
        const int bid2 = bid - 128;
        const int b = bid2 / 18;
        const int n0 = (bid2 % 18) * 64;
        const int nl = t & 63;
        const int cs = t >> 6;           // 0..3
        const int n = n0 + nl;
        const bool nvalid = n < N_NODES;
        const float* xb = x + (size_t)b * CN;
        float* outb = out + (size_t)b * OUT_STRIDE_B + (size_t)4 * CN;
#pragma unroll 4
        for (int cc = 0; cc < 64; ++cc) {
            int c = cc * 4 + cs;
            if (nvalid) {
                float v = xb[(size_t)c * N_NODES + n];
                outb[(size_t)c * N_NODES + n] = v;           // concat block 4 = x
                tile[c][nl] = __float2bfloat16(v);
            }
        }
        __syncthreads();
        const int half = t >> 7;             // 0..1
        const int c0 = (t & 127) * 2;
#pragma unroll
        for (int it = 0; it < 32; ++it) {
            int row = it * 2 + half;
            int nr = n0 + row;
            if (nr < N_NODES) {
                __hip_bfloat162 p;
                p.x = tile[c0][row];
                p.y = tile[c0 + 1][row];
                *(__hip_bfloat162*)(nodes + ((size_t)b * N_NODES + nr) * C_DIM + c0) = p;
            }
        }
    }
}

// ---- analytic mean-aggregate ----
__global__ __launch_bounds__(256)
void gather_kernel(const bf16* __restrict__ nodes, bf16* __restrict__ aggb)
{
    const int n = blockIdx.x;        // 0..1151
    const int c = threadIdx.x;
    if (n >= N_NODES) {
        aggb[(size_t)n * C_DIM + c] = __float2bfloat16(0.f);
        return;
    }
    const int i = n / GRID_G, j = n % GRID_G;
    float s = 0.f, d = 0.f;
    if (j >= 2)           { s += __bfloat162float(nodes[(size_t)(n - 2)  * C_DIM + c]); d += 1.f; }
    if (i >= 2)           { s += __bfloat162float(nodes[(size_t)(n - 66) * C_DIM + c]); d += 1.f; }
    if (i >= 2 && j >= 2) { s += __bfloat162float(nodes[(size_t)(n - 68) * C_DIM + c]); d += 1.f; }
    if (i >= 2 && j >= 1 && j <= 30)
                          { s += __bfloat162float(nodes[(size_t)(n - 64) * C_DIM + c]); d += 1.f; }
    aggb[(size_t)n * C_DIM + c] = __float2bfloat16(d > 0.f ? s / d : 0.f);
}

// ---- fused GEMM: out = elu(nodes@WrT^T + [agg@WlT^T] + bias), scrambled store ----
// 128x128 tile, 4 waves, 16x16x32 bf16 MFMA. 3-buffer LDS, 2-deep prefetch with
// counted s_waitcnt vmcnt(4) + raw s_barrier (never drains to 0 in steady state).
// XOR-swizzled LDS both-sides. XCD-aware block swizzle (nwg = 4360 = 8*545).
__global__ __launch_bounds__(256)
void gemm_kernel(const bf16* __restrict__ nodes, const bf16* __restrict__ agg,
                 const bf16* __restrict__ WrT, const bf16* __restrict__ WlT,
                 const float* __restrict__ bias, float* __restrict__ out)
{
    __shared__ bf16 Alds[3][128 * 32];
    __shared__ bf16 Blds[3][128 * 32];
    const int t = threadIdx.x;
    const int lane = t & 63;
    const int w = t >> 6;
    const unsigned bid = blockIdx.x;
    const unsigned swz = (bid & 7) * 545 + (bid >> 3);
    const int bcol = swz & 7;
    const int brow = swz >> 3;

    f32x4 acc[4][4] = {};

    // staging: phys 16B slot s holds logical slot s ^ ((row>>1)&3)
    const int tq = t >> 2;                               // rows 0..63 (+64 for issue 1)
    const int kk = (((t & 3) ^ ((tq >> 1) & 3)) << 3);
    const int wr = (w >> 1) << 6;
    const int wc = (w & 1) << 6;
    const int fr = lane & 15;
    const int kq = lane >> 4;
    const int swzr = (kq ^ ((fr >> 1) & 3)) << 3;        // phys slot for reads (shorts)

    char* AldsB = (char*)Alds;
    char* BldsB = (char*)Blds;
    const short* AldsS = (const short*)Alds;
    const short* BldsS = (const short*)Blds;

    const int nsteps = (brow * 128 < N_NODES) ? 16 : 8;
    const bf16* Abase0 = nodes + (size_t)brow * 128 * C_DIM;
    const bf16* Abase1 = agg + (size_t)brow * 128 * C_DIM;
    const bf16* Bbase0 = WrT + (size_t)bcol * 128 * C_DIM;
    const bf16* Bbase1 = WlT + (size_t)bcol * 128 * C_DIM;

    auto STAGE = [&](int s, int buf) {
        const int k0 = (s & 7) * 32;
        const bf16* Ag = (s < 8 ? Abase0 : Abase1) + (size_t)tq * C_DIM + k0 + kk;
        const bf16* Bg = (s < 8 ? Bbase0 : Bbase1) + (size_t)tq * C_DIM + k0 + kk;
        gload16(AldsB + buf * 8192 + w * 1024,        Ag);
        gload16(AldsB + buf * 8192 + 4096 + w * 1024, Ag + 64 * C_DIM);
        gload16(BldsB + buf * 8192 + w * 1024,        Bg);
        gload16(BldsB + buf * 8192 + 4096 + w * 1024, Bg + 64 * C_DIM);
    };

    STAGE(0, 0);
    STAGE(1, 1);                       // 8 vmem ops in flight
    int rb = 0;                        // buffer read at step s; write target cycles
    for (int s = 0; s < nsteps; ++s) {
        // wait only for STAGE(s); STAGE(s+1)'s 4 ops stay in flight across barrier
        if (s + 1 < nsteps) asm volatile("s_waitcnt vmcnt(4)" ::: "memory");
        else                asm volatile("s_waitcnt vmcnt(0)" ::: "memory");
        __builtin_amdgcn_s_barrier();
        if (s + 2 < nsteps) STAGE(s + 2, rb == 0 ? 2 : (rb == 1 ? 0 : 1));
        const short* Ab = AldsS + rb * 4096;
        const short* Bb = BldsS + rb * 4096;
        short8 av[4], bv[4];
#pragma unroll
        for (int m = 0; m < 4; ++m)
            av[m] = *(const short8*)(Ab + (wr + m * 16 + fr) * 32 + swzr);
#pragma unroll
        for (int n = 0; n < 4; ++n)
            bv[n] = *(const short8*)(Bb + (wc + n * 16 + fr) * 32 + swzr);
#pragma unroll
        for (int m = 0; m < 4; ++m)
#pragma unroll
            for (int n = 0; n < 4; ++n)
                acc[m][n] = __builtin_amdgcn_mfma_f32_16x16x32_bf16(
                    av[m], bv[n], acc[m][n], 0, 0, 0);
        rb = (rb == 2) ? 0 : rb + 1;
    }

    // epilogue: bias + fast ELU + scrambled store
    const int rq = (lane >> 4) * 4;
    const int r0 = brow * 128 + wr + rq;
    const unsigned bb0 = (unsigned)r0 / N_NODES;         // one divide per lane
    const int rsw = (int)((bb0 + 1) * N_NODES);
    const int colbase = bcol * 128 + wc + fr;
    size_t coff[4];
    float bi[4];
#pragma unroll
    for (int n = 0; n < 4; ++n) {
        int col = colbase + n * 16;
        coff[n] = (size_t)(col >> 8) * CN + (col & 255);
        bi[n] = bias[col];
    }
#pragma unroll
    for (int m = 0; m < 4; ++m) {
#pragma unroll
        for (int reg = 0; reg < 4; ++reg) {
            int r = r0 + m * 16 + reg;
            if (r < TOTAL) {
                int bb = (int)bb0 + (r >= rsw ? 1 : 0);
                int nn = r - bb * N_NODES;
                size_t base = (size_t)bb * OUT_STRIDE_B + (size_t)nn * C_DIM;
#pragma unroll
                for (int n = 0; n < 4; ++n) {
                    float v = acc[m][n][reg] + bi[n];
                    v = v > 0.f ? v : (__expf(v) - 1.0f);
                    out[base + coff[n]] = v;
                }
            }
        }
    }
}

extern "C" void kernel_launch(void* const* d_in, const int* in_sizes, int n_in,
                              void* d_out, int out_size, void* d_ws, size_t ws_size,
                              hipStream_t stream) {
    const float* x  = (const float*)d_in[0];
    const float* Wl = (const float*)d_in[1];
    const float* bl = (const float*)d_in[2];
    const float* Wr = (const float*)d_in[3];
    float* out = (float*)d_out;
    char* ws = (char*)d_ws;

    bf16* nodes = (bf16*)(ws + OFF_NODES);
    bf16* aggb  = (bf16*)(ws + OFF_AGGB);
    bf16* WlT   = (bf16*)(ws + OFF_WLT);
    bf16* WrT   = (bf16*)(ws + OFF_WRT);

    prep_kernel<<<128 + BATCH * 18, 256, 0, stream>>>(x, Wl, Wr, nodes, WlT, WrT, out);
    gather_kernel<<<AGG_ROWS, 256, 0, stream>>>(nodes, aggb);
    gemm_kernel<<<8 * 545, 256, 0, stream>>>(nodes, aggb, WrT, WlT, bl, out);
    // timing ablation: identical second launch; dur_us - (R4 baseline 157) = warm GEMM cost
    gemm_kernel<<<8 * 545, 256, 0, stream>>>(nodes, aggb, WrT, WlT, bl, out);
}

// Round 9
// 159.806 us; speedup vs baseline: 1.7255x; 1.7255x over previous
//
#include <hip/hip_runtime.h>
#include <hip/hip_bf16.h>
#include <stdint.h>

// StrideGraphSAGE on MI355X (gfx950).
// h_l = elu(agg @ Wl[l] + bl[l] + nodes @ Wr[l]); out = concat(h_0..h_3, x) along C.
// agg is nonzero only for rows < 1089 (un-offset edge_index bug in the reference);
// the edge set is the deterministic stride-2 grid pattern -> computed analytically.
//
// R9: GEMM rewritten as the proven 8-phase 256^2 schedule (T2+T3+T4+T5):
// BM=BN=256 (BN tile == one layer), BK=64, 8 waves, 128KB LDS (2 dbuf),
// 4 phases/K-step with register-subtile reuse, per-phase barrier pair,
// setprio around MFMA, one vmcnt(0) per K-step placed before the closing
// barrier, 3-bit XOR LDS swizzle both-sides, bijective XCD block swizzle.

#define C_DIM 256
#define GRID_G 33
#define N_NODES 1089
#define BATCH 64
#define TOTAL (BATCH * N_NODES)     // 69696
#define M_PAD 69760
#define CN (C_DIM * N_NODES)        // 278784
#define OUT_STRIDE_B (5 * CN)       // 1393920
#define NCOLS 1024
#define AGG_ROWS_PAD 1280           // 5 tiles of 256; rows 1089..1279 zeroed
#define MT 273                      // ceil(69696/256) row tiles
#define NWG (MT * 4)                // 1092

using bf16 = __hip_bfloat16;
typedef __attribute__((ext_vector_type(8))) short short8;
typedef __attribute__((ext_vector_type(4))) float f32x4;

// ---- workspace layout (bytes) ----
#define NODES_BYTES ((size_t)M_PAD * C_DIM * 2)        // 35,717,120
#define OFF_NODES   ((size_t)0)
#define OFF_AGGB    (NODES_BYTES)
#define AGGB_BYTES  ((size_t)AGG_ROWS_PAD * C_DIM * 2) // 655,360
#define OFF_WLT     (OFF_AGGB + AGGB_BYTES)
#define WT_BYTES    ((size_t)NCOLS * C_DIM * 2)        // 524,288
#define OFF_WRT     (OFF_WLT + WT_BYTES)

__device__ __forceinline__ void gload16(void* lds, const void* g) {
    __builtin_amdgcn_global_load_lds(
        (const __attribute__((address_space(1))) uint32_t*)g,
        (__attribute__((address_space(3))) uint32_t*)lds,
        16, 0, 0);
}

// ---- fused prep: blocks 0..127 transpose W -> WT bf16; blocks 128..1279:
// x [B,C,N] f32 -> nodes [B*N, C] bf16, and copy x into out concat-block 4 ----
__global__ __launch_bounds__(256)
void prep_kernel(const float* __restrict__ x,
                 const float* __restrict__ Wl, const float* __restrict__ Wr,
                 bf16* __restrict__ nodes, bf16* __restrict__ WlT, bf16* __restrict__ WrT,
                 float* __restrict__ out)
{
    __shared__ char smem[33792];
    const int t = threadIdx.x;
    const int bid = blockIdx.x;
    if (bid < 128) {
        float (*tile)[65] = (float(*)[65])smem;
        const int sel = bid & 1;
        const int l = (bid >> 1) & 3;
        const int kt = ((bid >> 3) & 3) * 64;
        const int ct = ((bid >> 5) & 3) * 64;
        const float* W = sel ? Wr : Wl;
        bf16* WT = sel ? WrT : WlT;
        const int tc = t & 63;
        const int tk = t >> 6;
#pragma unroll
        for (int i = 0; i < 16; ++i) {
            int kl = i * 4 + tk;
            tile[kl][tc] = W[((size_t)(l * 256 + kt + kl)) * 256 + ct + tc];
        }
        __syncthreads();
#pragma unroll
        for (int i = 0; i < 16; ++i) {
            int cl = i * 4 + tk;
            WT[((size_t)(l * 256 + ct + cl)) * 256 + kt + tc] = __float2bfloat16(tile[tc][cl]);
        }
    } else {
        bf16 (*tile)[66] = (bf16(*)[66])smem;
        const int bid2 = bid - 128;
        const int b = bid2 / 18;
        const int n0 = (bid2 % 18) * 64;
        const int nl = t & 63;
        const int cs = t >> 6;
        const int n = n0 + nl;
        const bool nvalid = n < N_NODES;
        const float* xb = x + (size_t)b * CN;
        float* outb = out + (size_t)b * OUT_STRIDE_B + (size_t)4 * CN;
#pragma unroll 4
        for (int cc = 0; cc < 64; ++cc) {
            int c = cc * 4 + cs;
            if (nvalid) {
                float v = xb[(size_t)c * N_NODES + n];
                outb[(size_t)c * N_NODES + n] = v;
                tile[c][nl] = __float2bfloat16(v);
            }
        }
        __syncthreads();
        const int half = t >> 7;
        const int c0 = (t & 127) * 2;
#pragma unroll
        for (int it = 0; it < 32; ++it) {
            int row = it * 2 + half;
            int nr = n0 + row;
            if (nr < N_NODES) {
                __hip_bfloat162 p;
                p.x = tile[c0][row];
                p.y = tile[c0 + 1][row];
                *(__hip_bfloat162*)(nodes + ((size_t)b * N_NODES + nr) * C_DIM + c0) = p;
            }
        }
    }
}

// ---- analytic mean-aggregate; rows N_NODES..1279 zeroed (GEMM tiles 0..4 read them) ----
__global__ __launch_bounds__(256)
void gather_kernel(const bf16* __restrict__ nodes, bf16* __restrict__ aggb)
{
    const int n = blockIdx.x;        // 0..1279
    const int c = threadIdx.x;
    if (n >= N_NODES) {
        aggb[(size_t)n * C_DIM + c] = __float2bfloat16(0.f);
        return;
    }
    const int i = n / GRID_G, j = n % GRID_G;
    float s = 0.f, d = 0.f;
    if (j >= 2)           { s += __bfloat162float(nodes[(size_t)(n - 2)  * C_DIM + c]); d += 1.f; }
    if (i >= 2)           { s += __bfloat162float(nodes[(size_t)(n - 66) * C_DIM + c]); d += 1.f; }
    if (i >= 2 && j >= 2) { s += __bfloat162float(nodes[(size_t)(n - 68) * C_DIM + c]); d += 1.f; }
    if (i >= 2 && j >= 1 && j <= 30)
                          { s += __bfloat162float(nodes[(size_t)(n - 64) * C_DIM + c]); d += 1.f; }
    aggb[(size_t)n * C_DIM + c] = __float2bfloat16(d > 0.f ? s / d : 0.f);
}

// ---- 8-phase-style 256^2 GEMM ----
// K-step kt: 0..3 = nodes@WrT (k0=kt*64); 4..7 = agg@WlT (brow<5 only).
// dbuf = kt&1. During kt's 4 phases, stage kt+1's 4 half-tiles (1/phase, 2 gloads).
// vmcnt(0) at end of phase 3 (before closing barrier) -> kt+1 data published.
__global__ __launch_bounds__(512)
void gemm_kernel(const bf16* __restrict__ nodes, const bf16* __restrict__ agg,
                 const bf16* __restrict__ WrT, const bf16* __restrict__ WlT,
                 const float* __restrict__ bias, float* __restrict__ out)
{
    extern __shared__ char Sb[];       // 131072: A[2][256][64] @0, B[2][256][64] @65536
    const int t = threadIdx.x;
    const int lane = t & 63;
    const int w = t >> 6;              // 0..7
    const int wm = w >> 2;             // 0..1  (row half: 128 rows)
    const int wn = w & 3;              // 0..3  (col quarter: 64 cols)
    const int fr = lane & 15;
    const int kq = lane >> 4;

    // bijective XCD swizzle: 1092 = 8*136 + 4 (m204). bcol fastest within an XCD.
    const unsigned bid = blockIdx.x;
    const unsigned xcd = bid & 7, loc = bid >> 3;
    const unsigned swz = (xcd < 4 ? xcd * 137u : 4u * 137u + (xcd - 4u) * 136u) + loc;
    const int bcol = swz & 3;          // == output layer
    const int brow = swz >> 2;

    const int NT = (brow * 256 < N_NODES) ? 8 : 4;
    const size_t Arow0 = (size_t)brow * 256;
    const size_t Brow0 = (size_t)bcol * 256;

    f32x4 acc[8][4] = {};

    // staging thread mapping: per 8KB issue, thread t covers row t>>3, phys slot t&7;
    // inverse-swizzle the SOURCE k-slot so reads can XOR (rule #21).
    const int srow = t >> 3;                                // 0..63
    const int sk = (((t & 7) ^ (srow & 7)) << 3);           // elem offset in K
    // read-side: phys 16B slot = (ks*4+kq) ^ (row&7); row&7 == fr&7 everywhere used
    const int so0 = ((0 * 4 + kq) ^ (fr & 7)) << 4;         // byte offsets
    const int so1 = ((1 * 4 + kq) ^ (fr & 7)) << 4;
    const int arow_b = (wm * 128 + fr) * 128;               // A base byte (row*128)
    const int brow_b = (wn * 64 + fr) * 128;                // B base byte

    auto STAGE_HALF = [&](int kt, int half, int isB) {
        const int buf = kt & 1;
        const int kk0 = ((kt & 3) << 6) + sk;
        if (!isB) {
            const bf16* src = (kt < 4 ? nodes : agg);
            const size_t gr = Arow0 + half * 128 + srow;
            char* dst = Sb + buf * 32768 + half * 16384 + w * 1024;
            gload16(dst,        src + gr * 256 + kk0);
            gload16(dst + 8192, src + (gr + 64) * 256 + kk0);
        } else {
            const bf16* src = (kt < 4 ? WrT : WlT);
            const size_t gr = Brow0 + half * 128 + srow;
            char* dst = Sb + 65536 + buf * 32768 + half * 16384 + w * 1024;
            gload16(dst,        src + gr * 256 + kk0);
            gload16(dst + 8192, src + (gr + 64) * 256 + kk0);
        }
    };

    // prologue: stage kt0 + kt1 fully (16 loads); wait kt0 (8 left in flight); publish
    STAGE_HALF(0, 0, 0); STAGE_HALF(0, 1, 0); STAGE_HALF(0, 0, 1); STAGE_HALF(0, 1, 1);
    STAGE_HALF(1, 0, 0); STAGE_HALF(1, 1, 0); STAGE_HALF(1, 0, 1); STAGE_HALF(1, 1, 1);
    asm volatile("s_waitcnt vmcnt(8)" ::: "memory");
    __builtin_amdgcn_s_barrier();

    short8 av[4][2], bv0[2][2], bv1[2][2];

    for (int kt = 0; kt < NT; ++kt) {
        const int ab = (kt & 1) * 32768;
        const int bb = 65536 + (kt & 1) * 32768;
        const bool pf = (kt + 1 < NT);

        // ---- phase 0: (mh=0, nh=0)  reads: A-half0 (8) + B nf0,1 (4) ----
#pragma unroll
        for (int i = 0; i < 4; ++i) {
            av[i][0] = *(const short8*)(Sb + ab + arow_b + i * 2048 + so0);
            av[i][1] = *(const short8*)(Sb + ab + arow_b + i * 2048 + so1);
        }
#pragma unroll
        for (int j = 0; j < 2; ++j) {
            bv0[j][0] = *(const short8*)(Sb + bb + brow_b + j * 2048 + so0);
            bv0[j][1] = *(const short8*)(Sb + bb + brow_b + j * 2048 + so1);
        }
        if (pf) STAGE_HALF(kt + 1, 0, 0);
        __builtin_amdgcn_s_barrier();
        asm volatile("s_waitcnt lgkmcnt(0)" ::: "memory");
        __builtin_amdgcn_sched_barrier(0);
        __builtin_amdgcn_s_setprio(1);
#pragma unroll
        for (int ks = 0; ks < 2; ++ks)
#pragma unroll
            for (int i = 0; i < 4; ++i)
#pragma unroll
                for (int j = 0; j < 2; ++j)
                    acc[i][j] = __builtin_amdgcn_mfma_f32_16x16x32_bf16(
                        av[i][ks], bv0[j][ks], acc[i][j], 0, 0, 0);
        __builtin_amdgcn_s_setprio(0);
        __builtin_amdgcn_s_barrier();

        // ---- phase 1: (0,1)  reads: B nf2,3 (4) ----
#pragma unroll
        for (int j = 0; j < 2; ++j) {
            bv1[j][0] = *(const short8*)(Sb + bb + brow_b + 4096 + j * 2048 + so0);
            bv1[j][1] = *(const short8*)(Sb + bb + brow_b + 4096 + j * 2048 + so1);
        }
        if (pf) STAGE_HALF(kt + 1, 1, 0);
        __builtin_amdgcn_s_barrier();
        asm volatile("s_waitcnt lgkmcnt(0)" ::: "memory");
        __builtin_amdgcn_sched_barrier(0);
        __builtin_amdgcn_s_setprio(1);
#pragma unroll
        for (int ks = 0; ks < 2; ++ks)
#pragma unroll
            for (int i = 0; i < 4; ++i)
#pragma unroll
                for (int j = 0; j < 2; ++j)
                    acc[i][2 + j] = __builtin_amdgcn_mfma_f32_16x16x32_bf16(
                        av[i][ks], bv1[j][ks], acc[i][2 + j], 0, 0, 0);
        __builtin_amdgcn_s_setprio(0);
        __builtin_amdgcn_s_barrier();

        // ---- phase 2: (1,1)  reads: A-half1 (8) ----
#pragma unroll
        for (int i = 0; i < 4; ++i) {
            av[i][0] = *(const short8*)(Sb + ab + arow_b + 8192 + i * 2048 + so0);
            av[i][1] = *(const short8*)(Sb + ab + arow_b + 8192 + i * 2048 + so1);
        }
        if (pf) STAGE_HALF(kt + 1, 0, 1);
        __builtin_amdgcn_s_barrier();
        asm volatile("s_waitcnt lgkmcnt(0)" ::: "memory");
        __builtin_amdgcn_sched_barrier(0);
        __builtin_amdgcn_s_setprio(1);
#pragma unroll
        for (int ks = 0; ks < 2; ++ks)
#pragma unroll
            for (int i = 0; i < 4; ++i)
#pragma unroll
                for (int j = 0; j < 2; ++j)
                    acc[4 + i][2 + j] = __builtin_amdgcn_mfma_f32_16x16x32_bf16(
                        av[i][ks], bv1[j][ks], acc[4 + i][2 + j], 0, 0, 0);
        __builtin_amdgcn_s_setprio(0);
        __builtin_amdgcn_s_barrier();

        // ---- phase 3: (1,0)  no reads (av half1 + bv0 held) ----
        if (pf) STAGE_HALF(kt + 1, 1, 1);
        __builtin_amdgcn_s_barrier();
        __builtin_amdgcn_s_setprio(1);
#pragma unroll
        for (int ks = 0; ks < 2; ++ks)
#pragma unroll
            for (int i = 0; i < 4; ++i)
#pragma unroll
                for (int j = 0; j < 2; ++j)
                    acc[4 + i][j] = __builtin_amdgcn_mfma_f32_16x16x32_bf16(
                        av[i][ks], bv0[j][ks], acc[4 + i][j], 0, 0, 0);
        __builtin_amdgcn_s_setprio(0);
        // wait for kt+1's staged loads, then publish via the closing barrier
        if (pf) asm volatile("s_waitcnt vmcnt(0)" ::: "memory");
        __builtin_amdgcn_s_barrier();
    }

    // ---- epilogue: bias + fast ELU + scrambled store (layer == bcol uniform) ----
    const int r0 = brow * 256 + wm * 128 + kq * 4;
    const unsigned bb0 = (unsigned)r0 / N_NODES;
    const int rsw = (int)((bb0 + 1) * N_NODES);
    float* outL = out + (size_t)bcol * CN;
    int cof[4];
    float bi[4];
#pragma unroll
    for (int nf = 0; nf < 4; ++nf) {
        int c = wn * 64 + nf * 16 + fr;
        cof[nf] = c;
        bi[nf] = bias[bcol * 256 + c];
    }
#pragma unroll
    for (int mf = 0; mf < 8; ++mf) {
#pragma unroll
        for (int reg = 0; reg < 4; ++reg) {
            int r = r0 + mf * 16 + reg;
            if (r < TOTAL) {
                int bb = (int)bb0 + (r >= rsw ? 1 : 0);
                int nn = r - bb * N_NODES;
                size_t base = (size_t)bb * OUT_STRIDE_B + (size_t)nn * C_DIM;
#pragma unroll
                for (int nf = 0; nf < 4; ++nf) {
                    float v = acc[mf][nf][reg] + bi[nf];
                    v = v > 0.f ? v : (__expf(v) - 1.0f);
                    outL[base + cof[nf]] = v;
                }
            }
        }
    }
}

extern "C" void kernel_launch(void* const* d_in, const int* in_sizes, int n_in,
                              void* d_out, int out_size, void* d_ws, size_t ws_size,
                              hipStream_t stream) {
    const float* x  = (const float*)d_in[0];
    const float* Wl = (const float*)d_in[1];
    const float* bl = (const float*)d_in[2];
    const float* Wr = (const float*)d_in[3];
    float* out = (float*)d_out;
    char* ws = (char*)d_ws;

    bf16* nodes = (bf16*)(ws + OFF_NODES);
    bf16* aggb  = (bf16*)(ws + OFF_AGGB);
    bf16* WlT   = (bf16*)(ws + OFF_WLT);
    bf16* WrT   = (bf16*)(ws + OFF_WRT);

    prep_kernel<<<128 + BATCH * 18, 256, 0, stream>>>(x, Wl, Wr, nodes, WlT, WrT, out);
    gather_kernel<<<AGG_ROWS_PAD, 256, 0, stream>>>(nodes, aggb);
    gemm_kernel<<<NWG, 512, 131072, stream>>>(nodes, aggb, WrT, WlT, bl, out);
}